// Round 16
// baseline (552.952 us; speedup 1.0000x reference)
//
#include <hip/hip_runtime.h>
#include <hip/hip_bf16.h>

#define BATCH 64
#define SEQ   256
#define EMB   64
#define QKVD  64
#define KD    8192      // L*EMB
#define ND    8192      // L*QKV
#define SEQD  16384     // SEQ*EMB (per-batch x row)
#define BKT   512       // k per tile: W row chunk = 2KB contiguous
#define NSUB  12        // n-subtiles (16 cols) per persistent block
#define NTOT  (NSUB * 16)  // 192 k-tiles per block (16 per subtile)

typedef __attribute__((ext_vector_type(8))) short bf16x8;
typedef __attribute__((ext_vector_type(4))) float f32x4;

struct WArgs { const float* W[6]; const float* b[6]; };

// branchless round-to-nearest-even fp32 -> bf16 bits (inputs are finite)
__device__ __forceinline__ short f2bf(float f) {
    unsigned u = __builtin_bit_cast(unsigned, f);
    u += 0x7fffu + ((u >> 16) & 1u);
    return (short)(u >> 16);
}

// async global->LDS, 16B per lane; LDS dest = wave-uniform base + lane*16
__device__ __forceinline__ void gl16(const void* g, void* l) {
    __builtin_amdgcn_global_load_lds(
        (const __attribute__((address_space(1))) void*)g,
        (__attribute__((address_space(3))) void*)l, 16, 0, 0);
}

__device__ __forceinline__ void barrier_fenced() {
    asm volatile("" ::: "memory");
    __builtin_amdgcn_s_barrier();
    asm volatile("" ::: "memory");
}

// ---------------- kernel 1: x fp32 -> bf16 ----------------------------------
__global__ __launch_bounds__(256)
void cvt_x_kernel(const float* __restrict__ x, short* __restrict__ xb) {
    const int i = (blockIdx.x * 256 + threadIdx.x) * 4;
    float4 v = *reinterpret_cast<const float4*>(x + i);
    short4 o;
    o.x = f2bf(v.x); o.y = f2bf(v.y); o.z = f2bf(v.z); o.w = f2bf(v.w);
    *reinterpret_cast<short4*>(xb + i) = o;
}

// ---------------- kernel 2: QKV projections ---------------------------------
// C[m][n] = sum_k xs[m,k]*W[n,k] + b[n], gi in [0,6).
// 256 persistent blocks (1/CU), 4 waves; block = 64m x 16n; wave = 16m x 16n.
// W: ring-2 [16 rows][512k]f32 (2x32KB), staged as TWO adjacent 1KB issues per
//   row -> 2KB contiguous DRAM runs (run-length lever: 256B->4.0, 512B->4.35,
//   1KB->4.83 TB/s measured). A: [64][512k]bf16 single 64KB, L2-resident,
//   1KB-contiguous issues. Total LDS 128KB.
// UNIFORM 192-tile stream (12 n-subtiles x 16 k-tiles) with the r9 ledger:
//   prologue W(0)x8/wave, A(0)x16, W(1)x8; per tile: vmcnt(8) -> barrier ->
//   compute -> [epilogue at subtile end] -> barrier -> stageA(t+1), stageW(t+2).
//   No per-subtile prologue stall (stages cross subtile boundaries naturally).
// XCD parity: even XCDs serve g=0 logicals, odd g=1 -> one 2MB A panel per L2.
__global__ __launch_bounds__(256, 1)
void qkv_gemm_kernel(const short* __restrict__ xb, WArgs wa,
                     float* __restrict__ qkv) {
    __shared__ __attribute__((aligned(16))) float W_lds[2][16 * BKT]; // 64KB
    __shared__ __attribute__((aligned(16))) short A_lds[64 * BKT];    // 64KB

    const int wv  = threadIdx.x >> 6;
    const int ln  = threadIdx.x & 63;
    const int r   = ln & 15;          // frag index (m-row for A, n-col for W)
    const int kb  = ln >> 4;          // k sub-block of 8 within 32
    const int key = r & 7;

    // persistent mapping: 256 blocks x 12 subtiles = 3072 logicals = 6gi x 512
    const int bid  = blockIdx.x;
    const int xcd  = bid & 7;
    const int idx  = bid >> 3;                 // 0..31
    const int lbase = (xcd & 1) * 1536 + ((xcd >> 1) * 32 + idx) * NSUB;

    f32x4 acc = {0.f, 0.f, 0.f, 0.f};

    auto stageW = [&](int tau) {               // 8 issues/wave: 4 rows x 2KB
        if (tau >= NTOT) return;
        const int logical = lbase + (tau >> 4);
        const int gi_ = logical >> 9;
        const int n0_ = (logical & 511) * 16;
        const char* Wp = (const char*)wa.W[gi_];
        float* slot = &W_lds[tau & 1][0];
        #pragma unroll
        for (int i = 0; i < 4; ++i) {
            const int row = wv * 4 + i;
            const size_t base =
                ((size_t)(n0_ + row) * KD + (size_t)(tau & 15) * BKT) * 4;
            #pragma unroll
            for (int j = 0; j < 2; ++j)        // adjacent 1KB+1KB = 2KB run
                gl16(Wp + base + j * 1024 + ((ln ^ (row & 7)) << 4),
                     (char*)slot + row * 2048 + j * 1024);
        }
    };

    auto stageA = [&](int tau) {               // 16 issues/wave: 1 row x 1KB
        if (tau >= NTOT) return;
        const int logical = lbase + (tau >> 4);
        const int g_ = (logical >> 9) / 3;
        const char* Ap = (const char*)(xb + (size_t)g_ * KD);
        #pragma unroll
        for (int i = 0; i < 16; ++i) {
            const int row = wv * 16 + i;
            gl16(Ap + ((size_t)row * SEQD + (size_t)(tau & 15) * BKT) * 2
                     + ((ln ^ (row & 7)) << 4),
                 (char*)&A_lds[0] + row * 1024);
        }
    };

    auto compute = [&](int tau) {
        const float* Wrow  = &W_lds[tau & 1][0] + r * BKT;
        const char*  Abase = (const char*)&A_lds[0] + (wv * 16 + r) * 1024;
        #pragma unroll
        for (int s = 0; s < 16; ++s) {
            const int half = s >> 3;
            const int c0   = (s & 7) * 8 + kb * 2;   // 16B chunk within 1KB half
            f32x4 w0 = *(const f32x4*)(Wrow + half * 256 + (((c0)     ^ key) << 2));
            f32x4 w1 = *(const f32x4*)(Wrow + half * 256 + (((c0 + 1) ^ key) << 2));
            bf16x8 bb;
            bb[0] = f2bf(w0[0]); bb[1] = f2bf(w0[1]);
            bb[2] = f2bf(w0[2]); bb[3] = f2bf(w0[3]);
            bb[4] = f2bf(w1[0]); bb[5] = f2bf(w1[1]);
            bb[6] = f2bf(w1[2]); bb[7] = f2bf(w1[3]);
            const int ca = (s * 4 + kb) ^ key;       // A 16B chunk (swizzled)
            const bf16x8 a = *(const bf16x8*)(Abase + (ca << 4));
            acc = __builtin_amdgcn_mfma_f32_16x16x32_bf16(a, bb, acc, 0, 0, 0);
        }
    };

    auto epilogue = [&](int sub) {
        const int logical = lbase + sub;
        const int gi_ = logical >> 9;
        const int n0_ = (logical & 511) * 16;
        const int nbr = n0_ + r;
        const float bias = wa.b[gi_][nbr];
        float* orow = qkv + (size_t)gi_ * (BATCH * ND) + nbr;
        #pragma unroll
        for (int reg = 0; reg < 4; ++reg) {
            const int m = wv * 16 + kb * 4 + reg;
            orow[(size_t)m * ND] = acc[reg] + bias;
        }
        acc[0] = 0.f; acc[1] = 0.f; acc[2] = 0.f; acc[3] = 0.f;
    };

    // prologue ledger: W(0)x8, A(0)x16, W(1)x8  (32 outstanding/wave)
    stageW(0);
    stageA(0);
    stageW(1);

    for (int tau = 0; tau < NTOT; ++tau) {
        if (tau < NTOT - 1) { asm volatile("s_waitcnt vmcnt(8)" ::: "memory"); }
        else                { asm volatile("s_waitcnt vmcnt(0)" ::: "memory"); }
        __builtin_amdgcn_sched_barrier(0);
        barrier_fenced();            // all waves' tile-tau stages in LDS
        compute(tau);
        if ((tau & 15) == 15) epilogue(tau >> 4);   // reg-private + g-stores
        barrier_fenced();            // WAR: A buf + W slot free to overwrite
        stageA(tau + 1);
        stageW(tau + 2);
    }
}

// ---------------- kernel 3: attention per (batch, group) -------------------
// scores[i][j] = Q[i,:]·K[j,:]; softmax over i (query axis); Z = attn·V; ×0.125
__global__ __launch_bounds__(256)
void attn_kernel(const float* __restrict__ qkv, float* __restrict__ out) {
    __shared__ float Ql[128 * 65];   // Q, then reused for V
    __shared__ float Kl[128 * 65];
    __shared__ float Sc[128 * 129];
    __shared__ float Pm[256];
    __shared__ float Ps[256];
    __shared__ float Rden[128];

    const int b = blockIdx.x;
    const int g = blockIdx.y;
    const int t = threadIdx.x;

    const float* __restrict__ Qg = qkv + ((size_t)(3 * g + 0) * BATCH + b) * ND;
    const float* __restrict__ Kg = qkv + ((size_t)(3 * g + 1) * BATCH + b) * ND;
    const float* __restrict__ Vg = qkv + ((size_t)(3 * g + 2) * BATCH + b) * ND;

    for (int e = t; e < 8192; e += 256) {
        const int i = e >> 6, k = e & 63;
        Ql[i * 65 + k] = Qg[e];
        Kl[i * 65 + k] = Kg[e];
    }
    __syncthreads();

    // scores: 8x8 register tile per thread
    {
        const int i0 = (t >> 4) * 8;
        const int j0 = (t & 15) * 8;
        float s[8][8];
        #pragma unroll
        for (int rr = 0; rr < 8; ++rr)
            #pragma unroll
            for (int cc = 0; cc < 8; ++cc) s[rr][cc] = 0.f;
        for (int k = 0; k < 64; ++k) {
            float qv[8], kv[8];
            #pragma unroll
            for (int rr = 0; rr < 8; ++rr) qv[rr] = Ql[(i0 + rr) * 65 + k];
            #pragma unroll
            for (int cc = 0; cc < 8; ++cc) kv[cc] = Kl[(j0 + cc) * 65 + k];
            #pragma unroll
            for (int rr = 0; rr < 8; ++rr)
                #pragma unroll
                for (int cc = 0; cc < 8; ++cc)
                    s[rr][cc] = fmaf(qv[rr], kv[cc], s[rr][cc]);
        }
        #pragma unroll
        for (int rr = 0; rr < 8; ++rr)
            #pragma unroll
            for (int cc = 0; cc < 8; ++cc)
                Sc[(i0 + rr) * 129 + (j0 + cc)] = s[rr][cc];
    }
    __syncthreads();

    // V fill (Q dead) + per-column partial max; column j, half h
    const int j = t & 127, h = t >> 7;
    {
        for (int e = t; e < 8192; e += 256) {
            const int i = e >> 6, k = e & 63;
            Ql[i * 65 + k] = Vg[e];
        }
        float m = -3.0e38f;
        for (int i = h * 64; i < h * 64 + 64; ++i)
            m = fmaxf(m, Sc[i * 129 + j]);
        Pm[h * 128 + j] = m;
    }
    __syncthreads();
    {
        const float m = fmaxf(Pm[j], Pm[128 + j]);
        float sum = 0.f;
        for (int i = h * 64; i < h * 64 + 64; ++i) {
            const float e = __expf(Sc[i * 129 + j] - m);
            Sc[i * 129 + j] = e;
            sum += e;
        }
        Ps[h * 128 + j] = sum;
    }
    __syncthreads();
    if (t < 128) Rden[t] = 1.0f / (Ps[t] + Ps[128 + t]);
    __syncthreads();

    // PV: 8 rows x 4 cols per thread
    {
        const int i0 = (t >> 4) * 8;
        const int k0 = (t & 15) * 4;
        float z[8][4];
        #pragma unroll
        for (int rr = 0; rr < 8; ++rr)
            #pragma unroll
            for (int cc = 0; cc < 4; ++cc) z[rr][cc] = 0.f;
        for (int jj = 0; jj < 128; ++jj) {
            const float rd = Rden[jj];
            float av[8], vv[4];
            #pragma unroll
            for (int rr = 0; rr < 8; ++rr) av[rr] = Sc[(i0 + rr) * 129 + jj] * rd;
            #pragma unroll
            for (int cc = 0; cc < 4; ++cc) vv[cc] = Ql[jj * 65 + k0 + cc];
            #pragma unroll
            for (int rr = 0; rr < 8; ++rr)
                #pragma unroll
                for (int cc = 0; cc < 4; ++cc)
                    z[rr][cc] = fmaf(av[rr], vv[cc], z[rr][cc]);
        }
        float* op = out + (size_t)b * (SEQ * QKVD) + (size_t)(g * 128) * QKVD + k0;
        #pragma unroll
        for (int rr = 0; rr < 8; ++rr) {
            float4 o;
            o.x = z[rr][0] * 0.125f; o.y = z[rr][1] * 0.125f;
            o.z = z[rr][2] * 0.125f; o.w = z[rr][3] * 0.125f;
            *reinterpret_cast<float4*>(op + (size_t)(i0 + rr) * QKVD) = o;
        }
    }
}

// ---------------- launcher --------------------------------------------------
extern "C" void kernel_launch(void* const* d_in, const int* in_sizes, int n_in,
                              void* d_out, int out_size, void* d_ws, size_t ws_size,
                              hipStream_t stream) {
    const float* x = (const float*)d_in[0];
    WArgs wa;
    for (int g = 0; g < 2; ++g)
        for (int q = 0; q < 3; ++q) {
            wa.W[g * 3 + q] = (const float*)d_in[1 + g * 6 + q * 2];
            wa.b[g * 3 + q] = (const float*)d_in[2 + g * 6 + q * 2];
        }

    short* xb  = (short*)d_ws;                                      // 2 MiB
    float* qkv = (float*)((char*)d_ws + (size_t)4 * 1024 * 1024);   // 12.6 MiB

    cvt_x_kernel<<<dim3(1024), dim3(256), 0, stream>>>(x, xb);
    qkv_gemm_kernel<<<dim3(256), dim3(256), 0, stream>>>(xb, wa, qkv);
    attn_kernel<<<dim3(BATCH, 2), dim3(256), 0, stream>>>(qkv, (float*)d_out);
}

// Round 17
// 346.127 us; speedup vs baseline: 1.5975x; 1.5975x over previous
//
#include <hip/hip_runtime.h>
#include <hip/hip_bf16.h>

#define BATCH 64
#define SEQ   256
#define EMB   64
#define QKVD  64
#define KD    8192      // L*EMB
#define ND    8192      // L*QKV
#define SEQD  16384     // SEQ*EMB (per-batch x row)
#define BKT   256       // k per tile: W row chunk = 1KB contiguous
#define NTK   (KD / BKT)   // 32 k-tiles

typedef __attribute__((ext_vector_type(8))) short bf16x8;
typedef __attribute__((ext_vector_type(4))) float f32x4;

struct WArgs { const float* W[6]; const float* b[6]; };

// branchless round-to-nearest-even fp32 -> bf16 bits (inputs are finite)
__device__ __forceinline__ short f2bf(float f) {
    unsigned u = __builtin_bit_cast(unsigned, f);
    u += 0x7fffu + ((u >> 16) & 1u);
    return (short)(u >> 16);
}

// async global->LDS, 16B per lane; LDS dest = wave-uniform base + lane*16
__device__ __forceinline__ void gl16(const void* g, void* l) {
    __builtin_amdgcn_global_load_lds(
        (const __attribute__((address_space(1))) void*)g,
        (__attribute__((address_space(3))) void*)l, 16, 0, 0);
}

__device__ __forceinline__ void barrier_fenced() {
    asm volatile("" ::: "memory");
    __builtin_amdgcn_s_barrier();
    asm volatile("" ::: "memory");
}

// ---------------- kernel 1: x fp32 -> bf16 ----------------------------------
__global__ __launch_bounds__(256)
void cvt_x_kernel(const float* __restrict__ x, short* __restrict__ xb) {
    const int i = (blockIdx.x * 256 + threadIdx.x) * 4;
    float4 v = *reinterpret_cast<const float4*>(x + i);
    short4 o;
    o.x = f2bf(v.x); o.y = f2bf(v.y); o.z = f2bf(v.z); o.w = f2bf(v.w);
    *reinterpret_cast<short4*>(xb + i) = o;
}

// ---------------- kernel 2: QKV projections ---------------------------------
// C[m][n] = sum_k xs[m,k] * W[n,k] + b[n], per gi in [0,6)
// 1 block/CU (160KB LDS), 4 waves, persistent over 3 n-tiles (6MB sequential W
// stream per block). BK=256: every W gl_lds issue = 1KB contiguous (DRAM
// row-buffer efficient). W double-buffered (2x64KB), A single-buffered (32KB).
// Counted vmcnt(16): W(t+1)'s 64KB stays in flight across compute(t).
// [Best-measured configuration, verified twice: r9=345us, r14=344.5us.
//  Pattern roofline: 1KB-run W stream = 4.83 TB/s real (run-length curve
//  256B->4.0, 512B->4.35, 1KB->4.83; 2KB unreachable within LDS/correctness).]
__global__ __launch_bounds__(256, 1)
void qkv_gemm_kernel(const short* __restrict__ xb, WArgs wa,
                     float* __restrict__ qkv) {
    __shared__ __attribute__((aligned(16))) float W_lds[2][64 * BKT]; // 128KB
    __shared__ __attribute__((aligned(16))) short A_lds[64 * BKT];    // 32KB

    const int wv = threadIdx.x >> 6;
    const int ln = threadIdx.x & 63;
    const int r  = ln & 15;           // n within wave tile / A row in frag
    const int kb = ln >> 4;           // k sub-block of 8 within 32
    const int key = r & 7;

    for (int nt = 0; nt < 3; ++nt) {
        const int logical = blockIdx.x * 3 + nt;
        const int gi = logical >> 7;               // 0..5
        const int n0 = (logical & 127) * 64;       // n-tile origin
        const int g  = gi / 3;

        const char*  __restrict__ Wb8 =
            (const char*)(wa.W[gi] + (size_t)(n0 + wv * 16) * KD);
        const short* __restrict__ Ag = xb + g * KD;

        f32x4 acc0 = {0.f, 0.f, 0.f, 0.f};
        f32x4 acc1 = acc0, acc2 = acc0, acc3 = acc0;

        auto stageW = [&](int t, int slot) {       // 16 issues = 16KB/wave
            const char* tb = Wb8 + (size_t)t * 1024;
            #pragma unroll
            for (int i = 0; i < 16; ++i) {         // 1 issue = 1KB contiguous
                gl16(tb + (size_t)i * (KD * 4) + ((ln ^ (i & 7)) << 4),
                     (char*)&W_lds[slot][0] + (wv * 16 + i) * 1024);
            }
        };
        auto stageA = [&](int t) {                 // 8 issues/wave, coop 64 rows
            #pragma unroll
            for (int j = 0; j < 8; ++j) {
                const int jj  = wv * 8 + j;        // issue covers rows 2jj,2jj+1
                const int row = 2 * jj + (ln >> 5);
                const int c   = (ln & 31) ^ (row & 7);
                gl16((const char*)(Ag + (size_t)row * SEQD) + (size_t)t * 512 + (c << 4),
                     (char*)&A_lds[0] + jj * 1024);
            }
        };

        auto compute = [&](int slot) {
            const float* Wrow = &W_lds[slot][0] + (wv * 16 + r) * BKT;
            const char*  Ab   = (const char*)&A_lds[0];
            #pragma unroll
            for (int s = 0; s < 8; ++s) {
                const int cg = s * 8 + kb * 2;
                f32x4 w0 = *(const f32x4*)(Wrow + (((cg)     ^ key) << 2));
                f32x4 w1 = *(const f32x4*)(Wrow + (((cg + 1) ^ key) << 2));
                bf16x8 bb;
                bb[0] = f2bf(w0[0]); bb[1] = f2bf(w0[1]);
                bb[2] = f2bf(w0[2]); bb[3] = f2bf(w0[3]);
                bb[4] = f2bf(w1[0]); bb[5] = f2bf(w1[1]);
                bb[6] = f2bf(w1[2]); bb[7] = f2bf(w1[3]);
                const int ca = (s * 4 + kb) ^ key;  // A 16B-chunk (swizzled)
                const bf16x8 a0 = *(const bf16x8*)(Ab + (r)      * 512 + (ca << 4));
                const bf16x8 a1 = *(const bf16x8*)(Ab + (r + 16) * 512 + (ca << 4));
                const bf16x8 a2 = *(const bf16x8*)(Ab + (r + 32) * 512 + (ca << 4));
                const bf16x8 a3 = *(const bf16x8*)(Ab + (r + 48) * 512 + (ca << 4));
                acc0 = __builtin_amdgcn_mfma_f32_16x16x32_bf16(a0, bb, acc0, 0, 0, 0);
                acc1 = __builtin_amdgcn_mfma_f32_16x16x32_bf16(a1, bb, acc1, 0, 0, 0);
                acc2 = __builtin_amdgcn_mfma_f32_16x16x32_bf16(a2, bb, acc2, 0, 0, 0);
                acc3 = __builtin_amdgcn_mfma_f32_16x16x32_bf16(a3, bb, acc3, 0, 0, 0);
            }
        };

        // prologue ledger order: W(0), A(0), W(1) -> vmcnt(16) at t=0 is exact
        stageW(0, 0);
        stageA(0);
        stageW(1, 1);

        for (int t = 0; t < NTK; ++t) {
            if (t < NTK - 2) { asm volatile("s_waitcnt vmcnt(16)" ::: "memory"); }
            else             { asm volatile("s_waitcnt vmcnt(0)"  ::: "memory"); }
            __builtin_amdgcn_sched_barrier(0);
            barrier_fenced();            // all waves' tile-t stages in LDS
            compute(t & 1);
            barrier_fenced();            // WAR: A buf + W slot free
            if (t + 1 < NTK) stageA(t + 1);
            if (t + 2 < NTK) stageW(t + 2, t & 1);
        }
        barrier_fenced();

        // D layout (m89): col = lane&15, row = (lane>>4)*4 + reg
        const int nbr = n0 + wv * 16 + r;
        const float bias = wa.b[gi][nbr];
        float* orow = qkv + (size_t)gi * (BATCH * ND) + nbr;
        #pragma unroll
        for (int reg = 0; reg < 4; ++reg) {
            const int m = kb * 4 + reg;
            orow[(size_t)(m)      * ND] = acc0[reg] + bias;
            orow[(size_t)(m + 16) * ND] = acc1[reg] + bias;
            orow[(size_t)(m + 32) * ND] = acc2[reg] + bias;
            orow[(size_t)(m + 48) * ND] = acc3[reg] + bias;
        }
    }
}

// ---------------- kernel 3: attention per (batch, group) -------------------
// scores[i][j] = Q[i,:]·K[j,:]; softmax over i (query axis); Z = attn·V; ×0.125
__global__ __launch_bounds__(256)
void attn_kernel(const float* __restrict__ qkv, float* __restrict__ out) {
    __shared__ float Ql[128 * 65];   // Q, then reused for V
    __shared__ float Kl[128 * 65];
    __shared__ float Sc[128 * 129];
    __shared__ float Pm[256];
    __shared__ float Ps[256];
    __shared__ float Rden[128];

    const int b = blockIdx.x;
    const int g = blockIdx.y;
    const int t = threadIdx.x;

    const float* __restrict__ Qg = qkv + ((size_t)(3 * g + 0) * BATCH + b) * ND;
    const float* __restrict__ Kg = qkv + ((size_t)(3 * g + 1) * BATCH + b) * ND;
    const float* __restrict__ Vg = qkv + ((size_t)(3 * g + 2) * BATCH + b) * ND;

    for (int e = t; e < 8192; e += 256) {
        const int i = e >> 6, k = e & 63;
        Ql[i * 65 + k] = Qg[e];
        Kl[i * 65 + k] = Kg[e];
    }
    __syncthreads();

    // scores: 8x8 register tile per thread
    {
        const int i0 = (t >> 4) * 8;
        const int j0 = (t & 15) * 8;
        float s[8][8];
        #pragma unroll
        for (int rr = 0; rr < 8; ++rr)
            #pragma unroll
            for (int cc = 0; cc < 8; ++cc) s[rr][cc] = 0.f;
        for (int k = 0; k < 64; ++k) {
            float qv[8], kv[8];
            #pragma unroll
            for (int rr = 0; rr < 8; ++rr) qv[rr] = Ql[(i0 + rr) * 65 + k];
            #pragma unroll
            for (int cc = 0; cc < 8; ++cc) kv[cc] = Kl[(j0 + cc) * 65 + k];
            #pragma unroll
            for (int rr = 0; rr < 8; ++rr)
                #pragma unroll
                for (int cc = 0; cc < 8; ++cc)
                    s[rr][cc] = fmaf(qv[rr], kv[cc], s[rr][cc]);
        }
        #pragma unroll
        for (int rr = 0; rr < 8; ++rr)
            #pragma unroll
            for (int cc = 0; cc < 8; ++cc)
                Sc[(i0 + rr) * 129 + (j0 + cc)] = s[rr][cc];
    }
    __syncthreads();

    // V fill (Q dead) + per-column partial max; column j, half h
    const int j = t & 127, h = t >> 7;
    {
        for (int e = t; e < 8192; e += 256) {
            const int i = e >> 6, k = e & 63;
            Ql[i * 65 + k] = Vg[e];
        }
        float m = -3.0e38f;
        for (int i = h * 64; i < h * 64 + 64; ++i)
            m = fmaxf(m, Sc[i * 129 + j]);
        Pm[h * 128 + j] = m;
    }
    __syncthreads();
    {
        const float m = fmaxf(Pm[j], Pm[128 + j]);
        float sum = 0.f;
        for (int i = h * 64; i < h * 64 + 64; ++i) {
            const float e = __expf(Sc[i * 129 + j] - m);
            Sc[i * 129 + j] = e;
            sum += e;
        }
        Ps[h * 128 + j] = sum;
    }
    __syncthreads();
    if (t < 128) Rden[t] = 1.0f / (Ps[t] + Ps[128 + t]);
    __syncthreads();

    // PV: 8 rows x 4 cols per thread
    {
        const int i0 = (t >> 4) * 8;
        const int k0 = (t & 15) * 4;
        float z[8][4];
        #pragma unroll
        for (int rr = 0; rr < 8; ++rr)
            #pragma unroll
            for (int cc = 0; cc < 4; ++cc) z[rr][cc] = 0.f;
        for (int jj = 0; jj < 128; ++jj) {
            const float rd = Rden[jj];
            float av[8], vv[4];
            #pragma unroll
            for (int rr = 0; rr < 8; ++rr) av[rr] = Sc[(i0 + rr) * 129 + jj] * rd;
            #pragma unroll
            for (int cc = 0; cc < 4; ++cc) vv[cc] = Ql[jj * 65 + k0 + cc];
            #pragma unroll
            for (int rr = 0; rr < 8; ++rr)
                #pragma unroll
                for (int cc = 0; cc < 4; ++cc)
                    z[rr][cc] = fmaf(av[rr], vv[cc], z[rr][cc]);
        }
        float* op = out + (size_t)b * (SEQ * QKVD) + (size_t)(g * 128) * QKVD + k0;
        #pragma unroll
        for (int rr = 0; rr < 8; ++rr) {
            float4 o;
            o.x = z[rr][0] * 0.125f; o.y = z[rr][1] * 0.125f;
            o.z = z[rr][2] * 0.125f; o.w = z[rr][3] * 0.125f;
            *reinterpret_cast<float4*>(op + (size_t)(i0 + rr) * QKVD) = o;
        }
    }
}

// ---------------- launcher --------------------------------------------------
extern "C" void kernel_launch(void* const* d_in, const int* in_sizes, int n_in,
                              void* d_out, int out_size, void* d_ws, size_t ws_size,
                              hipStream_t stream) {
    const float* x = (const float*)d_in[0];
    WArgs wa;
    for (int g = 0; g < 2; ++g)
        for (int q = 0; q < 3; ++q) {
            wa.W[g * 3 + q] = (const float*)d_in[1 + g * 6 + q * 2];
            wa.b[g * 3 + q] = (const float*)d_in[2 + g * 6 + q * 2];
        }

    short* xb  = (short*)d_ws;                                      // 2 MiB
    float* qkv = (float*)((char*)d_ws + (size_t)4 * 1024 * 1024);   // 12.6 MiB

    cvt_x_kernel<<<dim3(1024), dim3(256), 0, stream>>>(x, xb);
    qkv_gemm_kernel<<<dim3(256), dim3(256), 0, stream>>>(xb, wa, qkv);
    attn_kernel<<<dim3(BATCH, 2), dim3(256), 0, stream>>>(qkv, (float*)d_out);
}